// Round 2
// baseline (294.960 us; speedup 1.0000x reference)
//
#include <hip/hip_runtime.h>

typedef float  f32x4  __attribute__((ext_vector_type(4)));
typedef float  f32x16 __attribute__((ext_vector_type(16)));
typedef short  s16x8  __attribute__((ext_vector_type(8)));
typedef unsigned u32x2 __attribute__((ext_vector_type(2)));
typedef int    i32x4  __attribute__((ext_vector_type(4)));

#define SEQ 2048
#define DH  128
#define BN  32
#define NTILE 32   // tiles per KV-half (1024/32)

// fp32 -> 2x bf16 packed (RNE via native __bf16; compiler emits v_cvt_pk_bf16_f32)
__device__ __forceinline__ unsigned pk2bf(float a, float b){
  union { __bf16 h[2]; unsigned u; } x;
  x.h[0] = (__bf16)a; x.h[1] = (__bf16)b; return x.u;
}

__device__ __forceinline__ void gl16(const unsigned short* g, void* s){
  __builtin_amdgcn_global_load_lds(
      (const __attribute__((address_space(1))) void*)g,
      (__attribute__((address_space(3))) void*)s, 16, 0, 0);
}

// ---- pre-pass 1: K fp32 -> bf16 (row-major copy) ----
__global__ __launch_bounds__(256) void cvt_k(const float* __restrict__ in,
                                             unsigned short* __restrict__ out){
  size_t id = (size_t)blockIdx.x*256 + threadIdx.x;   // 2,097,152 threads x 4 elems
  f32x4 v = *(const f32x4*)(in + id*4);
  u32x2 o; o[0] = pk2bf(v[0], v[1]); o[1] = pk2bf(v[2], v[3]);
  *(u32x2*)(out + id*4) = o;
}

// ---- pre-pass 2: V fp32 [bh][kv][d] -> bf16 transposed Vt [bh][d][kv] ----
__global__ __launch_bounds__(256) void cvt_vt(const float* __restrict__ V,
                                              unsigned short* __restrict__ Vt){
  __shared__ float tile[32][33];
  const int bid = blockIdx.x;           // 32 bh * 64 kv-tiles * 4 d-tiles
  const int bh = bid >> 8, t5 = bid & 255;
  const int kv0 = (t5 >> 2) * 32, d0 = (t5 & 3) * 32;
  const int r = threadIdx.x >> 3, c = (threadIdx.x & 7) * 4;
  f32x4 v = *(const f32x4*)(V + ((size_t)bh*SEQ + kv0 + r)*DH + d0 + c);
  tile[r][c+0]=v[0]; tile[r][c+1]=v[1]; tile[r][c+2]=v[2]; tile[r][c+3]=v[3];
  __syncthreads();
  u32x2 o;
  o[0] = pk2bf(tile[c+0][r], tile[c+1][r]);
  o[1] = pk2bf(tile[c+2][r], tile[c+3][r]);
  *(u32x2*)(Vt + ((size_t)bh*DH + d0 + r)*SEQ + kv0 + c) = o;
}

// ---- main: flash attention fwd, non-causal ----
// 512 thr = 8 waves = 4 q-pairs x 2 KV-halves. Each wave: 32 q rows, 1024 kv.
// QK^T swapped (A=K,B=Q) -> per-lane softmax (q=ln). PV as O^T = V^T x P^T.
// P never touches LDS: cvt_pk + permlane32_swap builds the B-frag in-register.
// K/V arrive bf16 from ws via global_load_lds (pre-swizzled global addresses,
// linear LDS dest). Double-buffered; one barrier per tile. KV-halves merged
// through LDS in the epilogue.
__global__ __launch_bounds__(512, 4)
void sdpa_fwd(const float* __restrict__ Qg, const unsigned short* __restrict__ Kbf,
              const unsigned short* __restrict__ Vtb, float* __restrict__ Og)
{
  __shared__ __align__(16) char smem[68608];
  // loop region: (half,db) slabs of 16KB: [K 8KB | V 8KB], total 64KB
  // merge region (aliased, used after loop): obuf[4][32][132] f32 (67584B),
  //   mbuf[4][32] @67584, lbuf[4][32] @68096

  const int tid = threadIdx.x;
  const int w = tid >> 6, l = tid & 63, ln = l & 31, h2 = l >> 5;
  const int half = w >> 2, pair = w & 3;

  const int bid = (int)blockIdx.x;
  // XCD-chunked: 64 consecutive-swizzle blocks (4 bh x 16 qt) per XCD; 512%8==0.
  const int bh = ((bid & 7) << 2) | ((bid >> 3) & 3);
  const int qt = bid >> 5;

  const float* Qb = Qg + (size_t)bh*(SEQ*DH);
  const unsigned short* Kb = Kbf + (size_t)bh*(SEQ*DH);
  const unsigned short* Vb = Vtb + (size_t)bh*(SEQ*DH);  // [DH][SEQ]
  float* Ob = Og + (size_t)bh*(SEQ*DH);

  const int qrow = qt*128 + pair*32 + ln;
  const float qsc = 0.1275174156f;  // log2(e)/sqrt(128): softmax in exp2 domain

  // Q fragments (B-operand), 8 k-steps of 16
  s16x8 qf[8];
#pragma unroll
  for (int kc = 0; kc < 8; ++kc) {
    const float* p = Qb + (size_t)qrow*DH + kc*16 + h2*8;
    f32x4 a = *(const f32x4*)p, b = *(const f32x4*)(p+4);
    i32x4 t;
    t[0] = (int)pk2bf(a[0]*qsc, a[1]*qsc);
    t[1] = (int)pk2bf(a[2]*qsc, a[3]*qsc);
    t[2] = (int)pk2bf(b[0]*qsc, b[1]*qsc);
    t[3] = (int)pk2bf(b[2]*qsc, b[3]*qsc);
    qf[kc] = __builtin_bit_cast(s16x8, t);
  }

  // per-wave gload assignments: K insts {pair, pair+4}, V insts {pair, pair+4}
  const int i0 = pair, i1 = pair + 4;
  const unsigned short* kg0 = Kb + ((size_t)(half*1024) + (ln ^ ((2*i0+h2)&7)))*DH + 16*i0 + 8*h2;
  const unsigned short* kg1 = Kb + ((size_t)(half*1024) + (ln ^ ((2*i1+h2)&7)))*DH + 16*i1 + 8*h2;
  const unsigned short* vg0 = Vb + (size_t)(32*(i0&3) + (ln ^ ((2*(i0&3)+h2)&7)))*SEQ
                                 + half*1024 + 16*(i0>>2) + 8*h2;
  const unsigned short* vg1 = Vb + (size_t)(32*(i1&3) + (ln ^ ((2*(i1&3)+h2)&7)))*SEQ
                                 + half*1024 + 16*(i1>>2) + 8*h2;

  f32x16 ot[4];
#pragma unroll
  for (int dt = 0; dt < 4; ++dt)
#pragma unroll
    for (int r = 0; r < 16; ++r) ot[dt][r] = 0.f;
  float m_run = -1e30f, l_run = 0.f;

  auto issue = [&](int t, int db) {
    char* base = smem + (size_t)(half*2 + db)*16384;
    gl16(kg0 + (size_t)t*(BN*DH), base + i0*1024);
    gl16(kg1 + (size_t)t*(BN*DH), base + i1*1024);
    gl16(vg0 + t*BN, base + 8192 + i0*1024);
    gl16(vg1 + t*BN, base + 8192 + i1*1024);
  };

  issue(0, 0);
  __syncthreads();

  int db = 0;
  for (int t = 0; t < NTILE; ++t) {
    if (t + 1 < NTILE) issue(t + 1, db ^ 1);   // prefetch: lands by next barrier
    const char* base = smem + (size_t)(half*2 + db)*16384;

    // ---- QK^T: S^T[kv=ln-ish][q], 8 k-steps ----
    f32x16 sa;
#pragma unroll
    for (int r = 0; r < 16; ++r) sa[r] = 0.f;
#pragma unroll
    for (int kc = 0; kc < 8; ++kc) {
      const int frag = 2*kc + h2;
      s16x8 a = *(const s16x8*)(base + frag*512 + ((ln ^ (frag & 7)) << 4));
      sa = __builtin_amdgcn_mfma_f32_32x32x16_bf16(a, qf[kc], sa, 0, 0, 0);
    }

    // ---- online softmax, exp2 domain, per-row defer-max (THR=8) ----
    float tmax = fmaxf(sa[0], sa[1]);
#pragma unroll
    for (int r = 2; r < 16; ++r) tmax = fmaxf(tmax, sa[r]);
    tmax = fmaxf(tmax, __shfl_xor(tmax, 32));
    if (!__all(tmax <= m_run + 8.f)) {
      const float mnew = fmaxf(m_run, tmax);
      const float al = __builtin_amdgcn_exp2f(m_run - mnew);
      l_run *= al;
#pragma unroll
      for (int dt = 0; dt < 4; ++dt)
#pragma unroll
        for (int r = 0; r < 16; ++r) ot[dt][r] *= al;
      m_run = mnew;
    }
    float psum = 0.f;
#pragma unroll
    for (int r = 0; r < 16; ++r) {
      sa[r] = __builtin_amdgcn_exp2f(sa[r] - m_run);
      psum += sa[r];
    }
    psum += __shfl_xor(psum, 32);
    l_run += psum;

    // ---- P -> bf16 B-frags in-register (cvt_pk + permlane32_swap) ----
    i32x4 pw[2];
#pragma unroll
    for (int ks = 0; ks < 2; ++ks) {
      unsigned x0 = pk2bf(sa[8*ks+0], sa[8*ks+1]);
      unsigned x1 = pk2bf(sa[8*ks+2], sa[8*ks+3]);
      unsigned y0 = pk2bf(sa[8*ks+4], sa[8*ks+5]);
      unsigned y1 = pk2bf(sa[8*ks+6], sa[8*ks+7]);
      u32x2 s0 = __builtin_amdgcn_permlane32_swap(x0, y0, false, false);
      u32x2 s1 = __builtin_amdgcn_permlane32_swap(x1, y1, false, false);
      i32x4 b; b[0] = (int)s0[0]; b[1] = (int)s1[0]; b[2] = (int)s0[1]; b[3] = (int)s1[1];
      pw[ks] = b;
    }

    // ---- PV: O^T += V^T-frag x P^T-frag ----
#pragma unroll
    for (int ks = 0; ks < 2; ++ks) {
      s16x8 pb = __builtin_bit_cast(s16x8, pw[ks]);
#pragma unroll
      for (int dt = 0; dt < 4; ++dt) {
        const int frag = 2*(ks*4 + dt) + h2;
        s16x8 va = *(const s16x8*)(base + 8192 + frag*512 + ((ln ^ (frag & 7)) << 4));
        ot[dt] = __builtin_amdgcn_mfma_f32_32x32x16_bf16(va, pb, ot[dt], 0, 0, 0);
      }
    }

    __syncthreads();   // drains vmcnt -> next tile staged; LDS reads done for all
    db ^= 1;
  }

  // ---- merge KV-halves (upper waves publish; lower waves combine+store) ----
  float* obuf = (float*)smem;              // [4][32][132]
  float* mbuf = (float*)(smem + 67584);    // [4][32]
  float* lbuf = (float*)(smem + 68096);    // [4][32]
  if (half == 1) {
    mbuf[pair*32 + ln] = m_run;
    lbuf[pair*32 + ln] = l_run;
    float* orow = obuf + (size_t)(pair*32 + ln)*132;
#pragma unroll
    for (int dt = 0; dt < 4; ++dt)
#pragma unroll
      for (int rq = 0; rq < 4; ++rq) {
        f32x4 v;
        v[0] = ot[dt][rq*4+0]; v[1] = ot[dt][rq*4+1];
        v[2] = ot[dt][rq*4+2]; v[3] = ot[dt][rq*4+3];
        *(f32x4*)(orow + dt*32 + rq*8 + h2*4) = v;
      }
  }
  __syncthreads();
  if (half == 0) {
    const float m1 = mbuf[pair*32 + ln], l1 = lbuf[pair*32 + ln];
    const float ms = fmaxf(m_run, m1);
    const float a0 = __builtin_amdgcn_exp2f(m_run - ms);
    const float a1 = __builtin_amdgcn_exp2f(m1 - ms);
    const float inv = 1.f / (l_run*a0 + l1*a1);
    const float s0 = a0*inv, s1 = a1*inv;
    const float* orow = obuf + (size_t)(pair*32 + ln)*132;
#pragma unroll
    for (int dt = 0; dt < 4; ++dt)
#pragma unroll
      for (int rq = 0; rq < 4; ++rq) {
        f32x4 o1 = *(const f32x4*)(orow + dt*32 + rq*8 + h2*4);
        f32x4 o;
#pragma unroll
        for (int k = 0; k < 4; ++k) o[k] = ot[dt][rq*4+k]*s0 + o1[k]*s1;
        *(f32x4*)(Ob + (size_t)qrow*DH + dt*32 + rq*8 + h2*4) = o;
      }
  }
}

extern "C" void kernel_launch(void* const* d_in, const int* in_sizes, int n_in,
                              void* d_out, int out_size, void* d_ws, size_t ws_size,
                              hipStream_t stream)
{
  (void)in_sizes; (void)n_in; (void)out_size; (void)ws_size;
  const float* Q = (const float*)d_in[0];
  const float* K = (const float*)d_in[1];
  const float* V = (const float*)d_in[2];
  float* O = (float*)d_out;
  unsigned short* Kbf = (unsigned short*)d_ws;                    // 16,777,216 B
  unsigned short* Vt  = Kbf + (size_t)32*SEQ*DH;                  // 16,777,216 B

  hipLaunchKernelGGL(cvt_k,  dim3(8192), dim3(256), 0, stream, K, Kbf);
  hipLaunchKernelGGL(cvt_vt, dim3(8192), dim3(256), 0, stream, V, Vt);
  hipLaunchKernelGGL(sdpa_fwd, dim3(512), dim3(512), 0, stream, Q, Kbf, Vt, O);
}